// Round 1
// baseline (1394.550 us; speedup 1.0000x reference)
//
#include <hip/hip_runtime.h>
#include <hip/hip_bf16.h>

// Problem constants
constexpr int Bc  = 2;
constexpr int Sq  = 1024;   // query seq len
constexpr int CTX = 1024;
constexpr int Tt  = 2048;   // total kv len
constexpr int HID = 2048;
constexpr int NH  = 32;
constexpr int NKV = 8;
constexpr int HD  = 64;

// ---------------------------------------------------------------------------
// Tiled fp32 GEMM:  C[m,n] = sum_k A[m,k] * W[n,k]   (A: MxK row-major, W: NxK row-major)
// CONCAT: A rows are concat(target_context, hidden) along seq (per batch, T=2048, split at CTX)
// SPLITW: W/C split at column nsplit between (W1,C1) and (W2,C2); each C has width nsplit / N-nsplit
// BM=BN=128, BK=8, 256 threads, 8x8 per thread.
// ---------------------------------------------------------------------------
template<bool CONCAT, bool SPLITW>
__global__ __launch_bounds__(256)
void gemm_nt(const float* __restrict__ A1, const float* __restrict__ A2,
             const float* __restrict__ W1, const float* __restrict__ W2,
             float* __restrict__ C1, float* __restrict__ C2,
             int M, int N, int K, int nsplit)
{
    __shared__ __align__(16) float As[8][132];
    __shared__ __align__(16) float Ws[8][132];

    const int tid = threadIdx.x;
    const int m0 = blockIdx.y * 128;
    const int n0 = blockIdx.x * 128;

    // load assignment: each thread loads one float4 of A and one of W per BK step
    const int lr  = tid >> 1;          // 0..127 (row within tile)
    const int lk  = (tid & 1) * 4;     // 0 or 4

    const int gm = m0 + lr;
    const float* arow;
    if (CONCAT) {
        const int b = gm >> 11;        // / Tt
        const int t = gm & (Tt - 1);
        arow = (t < CTX) ? (A1 + (size_t)(b * CTX + t) * K)
                         : (A2 + (size_t)(b * Sq + (t - CTX)) * K);
    } else {
        arow = A1 + (size_t)gm * K;
    }
    const int gn = n0 + lr;
    const float* wrow;
    if (SPLITW) {
        wrow = (gn < nsplit) ? (W1 + (size_t)gn * K)
                             : (W2 + (size_t)(gn - nsplit) * K);
    } else {
        wrow = W1 + (size_t)gn * K;
    }

    const int tm = tid >> 4;   // 0..15
    const int tn = tid & 15;   // 0..15

    float acc[8][8];
    #pragma unroll
    for (int i = 0; i < 8; ++i)
        #pragma unroll
        for (int j = 0; j < 8; ++j) acc[i][j] = 0.0f;

    for (int k0 = 0; k0 < K; k0 += 8) {
        const float4 av = *reinterpret_cast<const float4*>(arow + k0 + lk);
        const float4 wv = *reinterpret_cast<const float4*>(wrow + k0 + lk);
        __syncthreads();
        As[lk + 0][lr] = av.x; As[lk + 1][lr] = av.y;
        As[lk + 2][lr] = av.z; As[lk + 3][lr] = av.w;
        Ws[lk + 0][lr] = wv.x; Ws[lk + 1][lr] = wv.y;
        Ws[lk + 2][lr] = wv.z; Ws[lk + 3][lr] = wv.w;
        __syncthreads();

        #pragma unroll
        for (int kk = 0; kk < 8; ++kk) {
            const float4 a0 = *reinterpret_cast<const float4*>(&As[kk][tm * 8]);
            const float4 a1 = *reinterpret_cast<const float4*>(&As[kk][tm * 8 + 4]);
            const float4 b0 = *reinterpret_cast<const float4*>(&Ws[kk][tn * 8]);
            const float4 b1 = *reinterpret_cast<const float4*>(&Ws[kk][tn * 8 + 4]);
            const float a[8] = {a0.x, a0.y, a0.z, a0.w, a1.x, a1.y, a1.z, a1.w};
            const float bb[8] = {b0.x, b0.y, b0.z, b0.w, b1.x, b1.y, b1.z, b1.w};
            #pragma unroll
            for (int i = 0; i < 8; ++i)
                #pragma unroll
                for (int j = 0; j < 8; ++j)
                    acc[i][j] = fmaf(a[i], bb[j], acc[i][j]);
        }
    }

    // store
    #pragma unroll
    for (int i = 0; i < 8; ++i) {
        const int gm2 = m0 + tm * 8 + i;
        const int gn2 = n0 + tn * 8;
        float* crow;
        if (SPLITW) {
            if (gn2 < nsplit) crow = C1 + (size_t)gm2 * nsplit + gn2;
            else              crow = C2 + (size_t)gm2 * (N - nsplit) + (gn2 - nsplit);
        } else {
            crow = C1 + (size_t)gm2 * N + gn2;
        }
        float4 o0, o1;
        o0.x = acc[i][0]; o0.y = acc[i][1]; o0.z = acc[i][2]; o0.w = acc[i][3];
        o1.x = acc[i][4]; o1.y = acc[i][5]; o1.z = acc[i][6]; o1.w = acc[i][7];
        *reinterpret_cast<float4*>(crow)     = o0;
        *reinterpret_cast<float4*>(crow + 4) = o1;
    }
}

// ---------------------------------------------------------------------------
// Fused per-head RMSNorm + RoPE, in place. One 64-lane wave per head-row.
// X layout: rows = (b, s, head), 64 contiguous dims per row.
// ---------------------------------------------------------------------------
__global__ __launch_bounds__(256)
void rms_rope(float* __restrict__ X, const float* __restrict__ gamma,
              const float* __restrict__ cosb, const float* __restrict__ sinb,
              int nheads, int slen, int pos_off)
{
    const int row  = blockIdx.x * 4 + (threadIdx.x >> 6);
    const int lane = threadIdx.x & 63;
    const int b    = row / (slen * nheads);
    const int rem  = row - b * slen * nheads;
    const int s    = rem / nheads;

    const size_t idx = (size_t)row * 64 + lane;
    const float x = X[idx];
    float ss = x * x;
    #pragma unroll
    for (int o = 32; o >= 1; o >>= 1) ss += __shfl_xor(ss, o);
    const float r = rsqrtf(ss * (1.0f / 64.0f) + 1e-6f);
    const float qn = x * r * gamma[lane];
    const float partner = __shfl_xor(qn, 32);
    const float rot = (lane < 32) ? -partner : partner;
    const int pos = pos_off + s;
    const size_t cidx = ((size_t)b * Tt + pos) * 64 + lane;
    X[idx] = qn * cosb[cidx] + rot * sinb[cidx];
}

// ---------------------------------------------------------------------------
// fp32 flash attention (non-causal, GQA). Grid: (B*NH, Sq/64). Block: 256.
// Per block: 64 q-rows, loop over T in 64-key tiles.
// Thread (tr=tid>>4, tc=tid&15): scores s[4][4] rows tr*4+i keys tc*4+j,
// output acc[4][4] rows tr*4+i dims tc*4+j. Row stats replicated across tc lanes.
// ---------------------------------------------------------------------------
__global__ __launch_bounds__(256)
void flash_attn(const float* __restrict__ Qw, const float* __restrict__ Kw,
                const float* __restrict__ Vw, float* __restrict__ Ow)
{
    const int bh = blockIdx.x;
    const int b  = bh >> 5;
    const int h  = bh & 31;
    const int g  = h >> 2;
    const int q0 = blockIdx.y << 6;
    const int tid = threadIdx.x;
    const int tr = tid >> 4;
    const int tc = tid & 15;

    __shared__ __align__(16) float Qt[64][68];   // [d][r]
    __shared__ __align__(16) float Kt[64][68];   // [d][t]
    __shared__ __align__(16) float Vs[64][68];   // [t][d]
    __shared__ __align__(16) float Pt[64][68];   // [t][r]

    // stage Q tile (transposed)
    {
        const int r  = tid >> 2;
        const int d0 = (tid & 3) << 4;
        const float* src = Qw + (((size_t)(b * Sq + q0 + r) * NH + h) << 6) + d0;
        #pragma unroll
        for (int i = 0; i < 4; ++i) {
            const float4 v = *reinterpret_cast<const float4*>(src + i * 4);
            Qt[d0 + i * 4 + 0][r] = v.x; Qt[d0 + i * 4 + 1][r] = v.y;
            Qt[d0 + i * 4 + 2][r] = v.z; Qt[d0 + i * 4 + 3][r] = v.w;
        }
    }

    float m_[4], l_[4], acc[4][4];
    #pragma unroll
    for (int i = 0; i < 4; ++i) {
        m_[i] = -1e30f; l_[i] = 0.0f;
        #pragma unroll
        for (int j = 0; j < 4; ++j) acc[i][j] = 0.0f;
    }

    for (int t0 = 0; t0 < Tt; t0 += 64) {
        __syncthreads();   // previous tile's PV done before overwriting LDS
        // stage K (transposed) and V
        {
            const int r  = tid >> 2;
            const int d0 = (tid & 3) << 4;
            const size_t base = ((size_t)(b * Tt + t0 + r) * NKV + g) << 6;
            const float* ksrc = Kw + base + d0;
            const float* vsrc = Vw + base + d0;
            #pragma unroll
            for (int i = 0; i < 4; ++i) {
                const float4 kv = *reinterpret_cast<const float4*>(ksrc + i * 4);
                Kt[d0 + i * 4 + 0][r] = kv.x; Kt[d0 + i * 4 + 1][r] = kv.y;
                Kt[d0 + i * 4 + 2][r] = kv.z; Kt[d0 + i * 4 + 3][r] = kv.w;
                *reinterpret_cast<float4*>(&Vs[r][d0 + i * 4]) =
                    *reinterpret_cast<const float4*>(vsrc + i * 4);
            }
        }
        __syncthreads();

        // QK^T
        float s[4][4];
        #pragma unroll
        for (int i = 0; i < 4; ++i)
            #pragma unroll
            for (int j = 0; j < 4; ++j) s[i][j] = 0.0f;
        #pragma unroll 4
        for (int d = 0; d < 64; ++d) {
            const float4 qv = *reinterpret_cast<const float4*>(&Qt[d][tr << 2]);
            const float4 kv = *reinterpret_cast<const float4*>(&Kt[d][tc << 2]);
            const float qa[4] = {qv.x, qv.y, qv.z, qv.w};
            const float ka[4] = {kv.x, kv.y, kv.z, kv.w};
            #pragma unroll
            for (int i = 0; i < 4; ++i)
                #pragma unroll
                for (int j = 0; j < 4; ++j)
                    s[i][j] = fmaf(qa[i], ka[j], s[i][j]);
        }

        // online softmax update
        float mx[4], resc[4], rs[4];
        #pragma unroll
        for (int i = 0; i < 4; ++i) {
            #pragma unroll
            for (int j = 0; j < 4; ++j) s[i][j] *= 0.125f;
            mx[i] = fmaxf(fmaxf(s[i][0], s[i][1]), fmaxf(s[i][2], s[i][3]));
        }
        #pragma unroll
        for (int o = 1; o < 16; o <<= 1)
            #pragma unroll
            for (int i = 0; i < 4; ++i) mx[i] = fmaxf(mx[i], __shfl_xor(mx[i], o));
        #pragma unroll
        for (int i = 0; i < 4; ++i) {
            const float mn = fmaxf(m_[i], mx[i]);
            resc[i] = __expf(m_[i] - mn);
            m_[i] = mn;
            float r0 = 0.0f;
            #pragma unroll
            for (int j = 0; j < 4; ++j) { s[i][j] = __expf(s[i][j] - mn); r0 += s[i][j]; }
            rs[i] = r0;
        }
        #pragma unroll
        for (int o = 1; o < 16; o <<= 1)
            #pragma unroll
            for (int i = 0; i < 4; ++i) rs[i] += __shfl_xor(rs[i], o);
        #pragma unroll
        for (int i = 0; i < 4; ++i) {
            l_[i] = l_[i] * resc[i] + rs[i];
            #pragma unroll
            for (int j = 0; j < 4; ++j) acc[i][j] *= resc[i];
        }
        // stage P transposed
        #pragma unroll
        for (int i = 0; i < 4; ++i)
            #pragma unroll
            for (int j = 0; j < 4; ++j)
                Pt[(tc << 2) + j][(tr << 2) + i] = s[i][j];
        __syncthreads();

        // PV
        #pragma unroll 4
        for (int t = 0; t < 64; ++t) {
            const float4 pv = *reinterpret_cast<const float4*>(&Pt[t][tr << 2]);
            const float4 vv = *reinterpret_cast<const float4*>(&Vs[t][tc << 2]);
            const float pa[4] = {pv.x, pv.y, pv.z, pv.w};
            const float va[4] = {vv.x, vv.y, vv.z, vv.w};
            #pragma unroll
            for (int i = 0; i < 4; ++i)
                #pragma unroll
                for (int j = 0; j < 4; ++j)
                    acc[i][j] = fmaf(pa[i], va[j], acc[i][j]);
        }
    }

    // finalize and write
    #pragma unroll
    for (int i = 0; i < 4; ++i) {
        const float inv = 1.0f / l_[i];
        float4 o;
        o.x = acc[i][0] * inv; o.y = acc[i][1] * inv;
        o.z = acc[i][2] * inv; o.w = acc[i][3] * inv;
        *reinterpret_cast<float4*>(
            Ow + (((size_t)(b * Sq + q0 + (tr << 2) + i) * NH + h) << 6) + (tc << 2)) = o;
    }
}

// ---------------------------------------------------------------------------
extern "C" void kernel_launch(void* const* d_in, const int* in_sizes, int n_in,
                              void* d_out, int out_size, void* d_ws, size_t ws_size,
                              hipStream_t stream)
{
    const float* hs   = (const float*)d_in[0];
    const float* tctx = (const float*)d_in[1];
    const float* cosb = (const float*)d_in[2];
    const float* sinb = (const float*)d_in[3];
    const float* Wq   = (const float*)d_in[4];
    const float* Wk   = (const float*)d_in[5];
    const float* Wv   = (const float*)d_in[6];
    const float* Wo   = (const float*)d_in[7];
    const float* qg   = (const float*)d_in[8];
    const float* kg   = (const float*)d_in[9];
    float* out = (float*)d_out;

    float* ws = (float*)d_ws;
    float* Qw = ws;                       // B*Sq*NH*HD   = 4194304 floats
    float* Kw = Qw + 4194304;             // B*Tt*NKV*HD  = 2097152
    float* Vw = Kw + 2097152;             // 2097152
    float* Aw = Vw + 2097152;             // 4194304

    // Q projection: (B*Sq x HID) @ Wq^T -> (B*Sq x 2048)
    gemm_nt<false, false><<<dim3(16, 16), 256, 0, stream>>>(
        hs, nullptr, Wq, nullptr, Qw, nullptr, Bc * Sq, NH * HD, HID, 0);

    // K,V projections fused: concat A rows, dual W/C. M=B*Tt=4096, N=1024
    gemm_nt<true, true><<<dim3(8, 32), 256, 0, stream>>>(
        tctx, hs, Wk, Wv, Kw, Vw, Bc * Tt, 2 * NKV * HD, HID, NKV * HD);

    // RMSNorm + RoPE (in place)
    rms_rope<<<(Bc * Sq * NH) / 4, 256, 0, stream>>>(Qw, qg, cosb, sinb, NH, Sq, CTX);
    rms_rope<<<(Bc * Tt * NKV) / 4, 256, 0, stream>>>(Kw, kg, cosb, sinb, NKV, Tt, 0);

    // flash attention
    flash_attn<<<dim3(Bc * NH, Sq / 64), 256, 0, stream>>>(Qw, Kw, Vw, Aw);

    // output projection
    gemm_nt<false, false><<<dim3(16, 16), 256, 0, stream>>>(
        Aw, nullptr, Wo, nullptr, out, nullptr, Bc * Sq, HID, NH * HD, 0);
}

// Round 2
// 964.604 us; speedup vs baseline: 1.4457x; 1.4457x over previous
//
#include <hip/hip_runtime.h>
#include <hip/hip_bf16.h>

// Problem constants
constexpr int Bc  = 2;
constexpr int Sq  = 1024;   // query seq len
constexpr int CTX = 1024;
constexpr int Tt  = 2048;   // total kv len
constexpr int HID = 2048;
constexpr int NH  = 32;
constexpr int NKV = 8;
constexpr int HD  = 64;

typedef __bf16 bf16_t;
typedef bf16_t bf16x8 __attribute__((ext_vector_type(8)));
typedef bf16_t bf16x4 __attribute__((ext_vector_type(4)));
typedef float  f32x4  __attribute__((ext_vector_type(4)));

// ---------------------------------------------------------------------------
// Tiled fp32 GEMM:  C[m,n] = sum_k A[m,k] * W[n,k]; C stored as OutT (fp32 or bf16)
// ---------------------------------------------------------------------------
template<bool CONCAT, bool SPLITW, typename OutT>
__global__ __launch_bounds__(256)
void gemm_nt(const float* __restrict__ A1, const float* __restrict__ A2,
             const float* __restrict__ W1, const float* __restrict__ W2,
             OutT* __restrict__ C1, OutT* __restrict__ C2,
             int M, int N, int K, int nsplit)
{
    __shared__ __align__(16) float As[8][132];
    __shared__ __align__(16) float Ws[8][132];

    const int tid = threadIdx.x;
    const int m0 = blockIdx.y * 128;
    const int n0 = blockIdx.x * 128;

    const int lr  = tid >> 1;          // 0..127
    const int lk  = (tid & 1) * 4;     // 0 or 4

    const int gm = m0 + lr;
    const float* arow;
    if (CONCAT) {
        const int b = gm >> 11;        // / Tt
        const int t = gm & (Tt - 1);
        arow = (t < CTX) ? (A1 + (size_t)(b * CTX + t) * K)
                         : (A2 + (size_t)(b * Sq + (t - CTX)) * K);
    } else {
        arow = A1 + (size_t)gm * K;
    }
    const int gn = n0 + lr;
    const float* wrow;
    if (SPLITW) {
        wrow = (gn < nsplit) ? (W1 + (size_t)gn * K)
                             : (W2 + (size_t)(gn - nsplit) * K);
    } else {
        wrow = W1 + (size_t)gn * K;
    }

    const int tm = tid >> 4;   // 0..15
    const int tn = tid & 15;   // 0..15

    float acc[8][8];
    #pragma unroll
    for (int i = 0; i < 8; ++i)
        #pragma unroll
        for (int j = 0; j < 8; ++j) acc[i][j] = 0.0f;

    for (int k0 = 0; k0 < K; k0 += 8) {
        const float4 av = *reinterpret_cast<const float4*>(arow + k0 + lk);
        const float4 wv = *reinterpret_cast<const float4*>(wrow + k0 + lk);
        __syncthreads();
        As[lk + 0][lr] = av.x; As[lk + 1][lr] = av.y;
        As[lk + 2][lr] = av.z; As[lk + 3][lr] = av.w;
        Ws[lk + 0][lr] = wv.x; Ws[lk + 1][lr] = wv.y;
        Ws[lk + 2][lr] = wv.z; Ws[lk + 3][lr] = wv.w;
        __syncthreads();

        #pragma unroll
        for (int kk = 0; kk < 8; ++kk) {
            const float4 a0 = *reinterpret_cast<const float4*>(&As[kk][tm * 8]);
            const float4 a1 = *reinterpret_cast<const float4*>(&As[kk][tm * 8 + 4]);
            const float4 b0 = *reinterpret_cast<const float4*>(&Ws[kk][tn * 8]);
            const float4 b1 = *reinterpret_cast<const float4*>(&Ws[kk][tn * 8 + 4]);
            const float a[8] = {a0.x, a0.y, a0.z, a0.w, a1.x, a1.y, a1.z, a1.w};
            const float bb[8] = {b0.x, b0.y, b0.z, b0.w, b1.x, b1.y, b1.z, b1.w};
            #pragma unroll
            for (int i = 0; i < 8; ++i)
                #pragma unroll
                for (int j = 0; j < 8; ++j)
                    acc[i][j] = fmaf(a[i], bb[j], acc[i][j]);
        }
    }

    #pragma unroll
    for (int i = 0; i < 8; ++i) {
        const int gm2 = m0 + tm * 8 + i;
        const int gn2 = n0 + tn * 8;
        OutT* crow;
        if (SPLITW) {
            if (gn2 < nsplit) crow = C1 + (size_t)gm2 * nsplit + gn2;
            else              crow = C2 + (size_t)gm2 * (N - nsplit) + (gn2 - nsplit);
        } else {
            crow = C1 + (size_t)gm2 * N + gn2;
        }
        if constexpr (sizeof(OutT) == 2) {
            bf16x8 o;
            #pragma unroll
            for (int j = 0; j < 8; ++j) o[j] = (bf16_t)acc[i][j];
            *reinterpret_cast<bf16x8*>(crow) = o;
        } else {
            float4 o0, o1;
            o0.x = acc[i][0]; o0.y = acc[i][1]; o0.z = acc[i][2]; o0.w = acc[i][3];
            o1.x = acc[i][4]; o1.y = acc[i][5]; o1.z = acc[i][6]; o1.w = acc[i][7];
            *reinterpret_cast<float4*>(crow)     = o0;
            *reinterpret_cast<float4*>(crow + 4) = o1;
        }
    }
}

// ---------------------------------------------------------------------------
// Fused per-head RMSNorm + RoPE, in place on bf16. One 64-lane wave per row.
// ---------------------------------------------------------------------------
__global__ __launch_bounds__(256)
void rms_rope(bf16_t* __restrict__ X, const float* __restrict__ gamma,
              const float* __restrict__ cosb, const float* __restrict__ sinb,
              int nheads, int slen, int pos_off)
{
    const int row  = blockIdx.x * 4 + (threadIdx.x >> 6);
    const int lane = threadIdx.x & 63;
    const int b    = row / (slen * nheads);
    const int rem  = row - b * slen * nheads;
    const int s    = rem / nheads;

    const size_t idx = (size_t)row * 64 + lane;
    const float x = (float)X[idx];
    float ss = x * x;
    #pragma unroll
    for (int o = 32; o >= 1; o >>= 1) ss += __shfl_xor(ss, o);
    const float r = rsqrtf(ss * (1.0f / 64.0f) + 1e-6f);
    const float qn = x * r * gamma[lane];
    const float partner = __shfl_xor(qn, 32);
    const float rot = (lane < 32) ? -partner : partner;
    const int pos = pos_off + s;
    const size_t cidx = ((size_t)b * Tt + pos) * 64 + lane;
    X[idx] = (bf16_t)(qn * cosb[cidx] + rot * sinb[cidx]);
}

// ---------------------------------------------------------------------------
// bf16 MFMA flash attention. Grid: (B*NH, Sq/64). Block: 256 (4 waves).
// Wave w owns q-rows q0+w*16..+15. KV tile = 64.
// QK^T swapped (S^T = K*Q^T): C-frag lane l holds S[q=l&15][k=kt*16+(l>>4)*4+j].
// PV as O^T = V^T * P^T: C-frag lane l holds O[q=l&15][d=dt*16+(l>>4)*4+j].
// ---------------------------------------------------------------------------
__global__ __launch_bounds__(256)
void flash_mfma(const bf16_t* __restrict__ Qb, const bf16_t* __restrict__ Kb,
                const bf16_t* __restrict__ Vb, float* __restrict__ Ow)
{
    const int bh = blockIdx.x;
    const int b  = bh >> 5;
    const int h  = bh & 31;
    const int g  = h >> 2;
    const int q0 = blockIdx.y << 6;
    const int tid  = threadIdx.x;
    const int wave = tid >> 6;
    const int lane = tid & 63;
    const int lr = lane & 15;   // q (or row) index within fragment
    const int lg = lane >> 4;   // k-slot group

    __shared__ __align__(16) bf16_t Kt[64][72];      // [k][d]
    __shared__ __align__(16) bf16_t Vt[64][72];      // [d][t]
    __shared__ __align__(16) bf16_t Pq[4][16][72];   // per-wave [q][t]

    // Q fragments, direct global->reg (B-operand of K*Q^T):
    // lane supplies Q[q = lr][d = ds*32 + lg*8 + j]
    bf16x8 qf[2];
    {
        const bf16_t* qp = Qb + ((size_t)((b * Sq + q0 + wave * 16 + lr) * NH + h)) * 64 + lg * 8;
        qf[0] = *reinterpret_cast<const bf16x8*>(qp);
        qf[1] = *reinterpret_cast<const bf16x8*>(qp + 32);
    }

    float m_ = -1e30f, l_ = 0.0f;
    f32x4 oacc[4];
    #pragma unroll
    for (int dt = 0; dt < 4; ++dt)
        #pragma unroll
        for (int j = 0; j < 4; ++j) oacc[dt][j] = 0.0f;

    for (int t0 = 0; t0 < Tt; t0 += 64) {
        __syncthreads();   // previous iteration's PV reads done
        // stage K tile: [k][d], bf16 copy
        {
            const int kr = tid >> 2;
            const int c  = (tid & 3) * 16;
            const bf16_t* kp = Kb + ((size_t)((b * Tt + t0 + kr) * NKV + g)) * 64 + c;
            *reinterpret_cast<bf16x8*>(&Kt[kr][c])     = *reinterpret_cast<const bf16x8*>(kp);
            *reinterpret_cast<bf16x8*>(&Kt[kr][c + 8]) = *reinterpret_cast<const bf16x8*>(kp + 8);
        }
        // stage V tile transposed: [d][t]; thread owns a 4x4 block
        {
            const int tb = tid >> 4;      // t-block 0..15
            const int db = tid & 15;      // d-block 0..15
            const bf16_t* vp = Vb + ((size_t)((b * Tt + t0 + tb * 4) * NKV + g)) * 64 + db * 4;
            const bf16x4 v0 = *reinterpret_cast<const bf16x4*>(vp);
            const bf16x4 v1 = *reinterpret_cast<const bf16x4*>(vp + NKV * 64);
            const bf16x4 v2 = *reinterpret_cast<const bf16x4*>(vp + 2 * NKV * 64);
            const bf16x4 v3 = *reinterpret_cast<const bf16x4*>(vp + 3 * NKV * 64);
            #pragma unroll
            for (int j = 0; j < 4; ++j) {
                bf16x4 w;
                w[0] = v0[j]; w[1] = v1[j]; w[2] = v2[j]; w[3] = v3[j];
                *reinterpret_cast<bf16x4*>(&Vt[db * 4 + j][tb * 4]) = w;
            }
        }
        __syncthreads();

        // QK^T (swapped): per key-subtile kt, 2 K-steps over d
        f32x4 sc[4];
        #pragma unroll
        for (int kt = 0; kt < 4; ++kt) {
            #pragma unroll
            for (int j = 0; j < 4; ++j) sc[kt][j] = 0.0f;
            const bf16x8 kf0 = *reinterpret_cast<const bf16x8*>(&Kt[kt * 16 + lr][lg * 8]);
            const bf16x8 kf1 = *reinterpret_cast<const bf16x8*>(&Kt[kt * 16 + lr][32 + lg * 8]);
            sc[kt] = __builtin_amdgcn_mfma_f32_16x16x32_bf16(kf0, qf[0], sc[kt], 0, 0, 0);
            sc[kt] = __builtin_amdgcn_mfma_f32_16x16x32_bf16(kf1, qf[1], sc[kt], 0, 0, 0);
        }

        // online softmax: lane holds 16 scores for q = lr
        float p[16];
        float mx = -1e30f;
        #pragma unroll
        for (int kt = 0; kt < 4; ++kt)
            #pragma unroll
            for (int j = 0; j < 4; ++j) {
                const float v = sc[kt][j] * 0.125f;
                p[kt * 4 + j] = v;
                mx = fmaxf(mx, v);
            }
        mx = fmaxf(mx, __shfl_xor(mx, 16));
        mx = fmaxf(mx, __shfl_xor(mx, 32));
        const float mn = fmaxf(m_, mx);
        const float resc = __expf(m_ - mn);
        m_ = mn;
        float rs = 0.0f;
        #pragma unroll
        for (int i = 0; i < 16; ++i) { p[i] = __expf(p[i] - mn); rs += p[i]; }
        rs += __shfl_xor(rs, 16);
        rs += __shfl_xor(rs, 32);
        l_ = l_ * resc + rs;
        #pragma unroll
        for (int dt = 0; dt < 4; ++dt)
            #pragma unroll
            for (int j = 0; j < 4; ++j) oacc[dt][j] *= resc;

        // write P (bf16) to per-wave LDS: Pq[wave][q=lr][t = kt*16 + lg*4 + j]
        #pragma unroll
        for (int kt = 0; kt < 4; ++kt) {
            bf16x4 pw;
            #pragma unroll
            for (int j = 0; j < 4; ++j) pw[j] = (bf16_t)p[kt * 4 + j];
            *reinterpret_cast<bf16x4*>(&Pq[wave][lr][kt * 16 + lg * 4]) = pw;
        }
        __syncthreads();   // P visible (and orders Vt for PV)

        // PV: O^T = V^T * P^T; B-frag: P[q=lr][ts*32 + lg*8 + j]
        bf16x8 pb[2];
        pb[0] = *reinterpret_cast<const bf16x8*>(&Pq[wave][lr][lg * 8]);
        pb[1] = *reinterpret_cast<const bf16x8*>(&Pq[wave][lr][32 + lg * 8]);
        #pragma unroll
        for (int dt = 0; dt < 4; ++dt) {
            const bf16x8 vf0 = *reinterpret_cast<const bf16x8*>(&Vt[dt * 16 + lr][lg * 8]);
            const bf16x8 vf1 = *reinterpret_cast<const bf16x8*>(&Vt[dt * 16 + lr][32 + lg * 8]);
            oacc[dt] = __builtin_amdgcn_mfma_f32_16x16x32_bf16(vf0, pb[0], oacc[dt], 0, 0, 0);
            oacc[dt] = __builtin_amdgcn_mfma_f32_16x16x32_bf16(vf1, pb[1], oacc[dt], 0, 0, 0);
        }
    }

    // finalize: lane holds O[q = lr][d = dt*16 + lg*4 + j]
    const float inv = 1.0f / l_;
    #pragma unroll
    for (int dt = 0; dt < 4; ++dt) {
        float4 o;
        o.x = oacc[dt][0] * inv; o.y = oacc[dt][1] * inv;
        o.z = oacc[dt][2] * inv; o.w = oacc[dt][3] * inv;
        *reinterpret_cast<float4*>(
            Ow + ((size_t)((b * Sq + q0 + wave * 16 + lr) * NH + h)) * 64 + dt * 16 + lg * 4) = o;
    }
}

// ---------------------------------------------------------------------------
extern "C" void kernel_launch(void* const* d_in, const int* in_sizes, int n_in,
                              void* d_out, int out_size, void* d_ws, size_t ws_size,
                              hipStream_t stream)
{
    const float* hs   = (const float*)d_in[0];
    const float* tctx = (const float*)d_in[1];
    const float* cosb = (const float*)d_in[2];
    const float* sinb = (const float*)d_in[3];
    const float* Wq   = (const float*)d_in[4];
    const float* Wk   = (const float*)d_in[5];
    const float* Wv   = (const float*)d_in[6];
    const float* Wo   = (const float*)d_in[7];
    const float* qg   = (const float*)d_in[8];
    const float* kg   = (const float*)d_in[9];
    float* out = (float*)d_out;

    float*  ws = (float*)d_ws;
    float*  Aw = ws;                                   // 4194304 f32 (16MB)
    bf16_t* Qb = (bf16_t*)(ws + 4194304);              // 4194304 bf16 (8MB)
    bf16_t* Kb = Qb + 4194304;                         // 2097152 bf16 (4MB)
    bf16_t* Vb = Kb + 2097152;                         // 2097152 bf16 (4MB)

    // Q projection -> bf16
    gemm_nt<false, false, bf16_t><<<dim3(16, 16), 256, 0, stream>>>(
        hs, nullptr, Wq, nullptr, Qb, nullptr, Bc * Sq, NH * HD, HID, 0);

    // K,V projections fused (concat rows, dual W/C) -> bf16
    gemm_nt<true, true, bf16_t><<<dim3(8, 32), 256, 0, stream>>>(
        tctx, hs, Wk, Wv, Kb, Vb, Bc * Tt, 2 * NKV * HD, HID, NKV * HD);

    // RMSNorm + RoPE in place (bf16)
    rms_rope<<<(Bc * Sq * NH) / 4, 256, 0, stream>>>(Qb, qg, cosb, sinb, NH, Sq, CTX);
    rms_rope<<<(Bc * Tt * NKV) / 4, 256, 0, stream>>>(Kb, kg, cosb, sinb, NKV, Tt, 0);

    // flash attention (bf16 MFMA), fp32 output
    flash_mfma<<<dim3(Bc * NH, Sq / 64), 256, 0, stream>>>(Qb, Kb, Vb, Aw);

    // output projection (fp32)
    gemm_nt<false, false, float><<<dim3(16, 16), 256, 0, stream>>>(
        Aw, nullptr, Wo, nullptr, out, nullptr, Bc * Sq, HID, NH * HD, 0);
}

// Round 3
// 268.261 us; speedup vs baseline: 5.1985x; 3.5958x over previous
//
#include <hip/hip_runtime.h>
#include <hip/hip_bf16.h>

// Problem constants
constexpr int Bc  = 2;
constexpr int Sq  = 1024;   // query seq len
constexpr int CTX = 1024;
constexpr int Tt  = 2048;   // total kv len
constexpr int HID = 2048;
constexpr int NH  = 32;
constexpr int NKV = 8;
constexpr int HD  = 64;

typedef __bf16 bf16_t;
typedef bf16_t bf16x8 __attribute__((ext_vector_type(8)));
typedef bf16_t bf16x4 __attribute__((ext_vector_type(4)));
typedef float  f32x4  __attribute__((ext_vector_type(4)));

// ---------------------------------------------------------------------------
// async global->LDS, 16B per lane. LDS dest must be wave-uniform base
// (HW adds lane*16); global src is per-lane.
// ---------------------------------------------------------------------------
__device__ __forceinline__ void gload16(const bf16_t* g, bf16_t* l)
{
    __builtin_amdgcn_global_load_lds(
        (const __attribute__((address_space(1))) void*)g,
        (__attribute__((address_space(3))) void*)l, 16, 0, 0);
}

// ---------------------------------------------------------------------------
// fp32 -> bf16 elementwise convert (8 elems/thread)
// ---------------------------------------------------------------------------
__global__ __launch_bounds__(256)
void cvt_bf16(const float* __restrict__ src, bf16_t* __restrict__ dst, int n)
{
    const int i = (blockIdx.x * 256 + threadIdx.x) * 8;
    if (i >= n) return;
    const float4 a = *reinterpret_cast<const float4*>(src + i);
    const float4 b = *reinterpret_cast<const float4*>(src + i + 4);
    bf16x8 o;
    o[0] = (bf16_t)a.x; o[1] = (bf16_t)a.y; o[2] = (bf16_t)a.z; o[3] = (bf16_t)a.w;
    o[4] = (bf16_t)b.x; o[5] = (bf16_t)b.y; o[6] = (bf16_t)b.z; o[7] = (bf16_t)b.w;
    *reinterpret_cast<bf16x8*>(dst + i) = o;
}

// fp32 -> bf16 with per-batch concat placement: src [B][2^21], dst [B][2^22] at dstOff
__global__ __launch_bounds__(256)
void cvt_concat(const float* __restrict__ src, bf16_t* __restrict__ dst, int dstOff)
{
    const int i   = (blockIdx.x * 256 + threadIdx.x) * 8;
    const int b   = i >> 21;
    const int rem = i & ((1 << 21) - 1);
    const float4 a = *reinterpret_cast<const float4*>(src + i);
    const float4 c = *reinterpret_cast<const float4*>(src + i + 4);
    bf16x8 o;
    o[0] = (bf16_t)a.x; o[1] = (bf16_t)a.y; o[2] = (bf16_t)a.z; o[3] = (bf16_t)a.w;
    o[4] = (bf16_t)c.x; o[5] = (bf16_t)c.y; o[6] = (bf16_t)c.z; o[7] = (bf16_t)c.w;
    *reinterpret_cast<bf16x8*>(dst + (((size_t)b << 22) + dstOff + rem)) = o;
}

// ---------------------------------------------------------------------------
// bf16 MFMA GEMM:  C[m,n] = sum_k A[m,k] * B[n,k]   (both row-major K-contig)
// BM=BN=128, BK=32, 256 threads (4 waves, 2x2), 4x4 16x16x32 frags per wave.
// Double-buffered LDS via global_load_lds (2-phase schedule).
// AMAP=1: A row m remapped to kv-concat hidden rows: (m>>10)*2048 + 1024 + (m&1023)
// ---------------------------------------------------------------------------
template<int AMAP, typename OutT>
__global__ __launch_bounds__(256)
void gemm_mfma(const bf16_t* __restrict__ A, const bf16_t* __restrict__ Bw,
               OutT* __restrict__ C, int M, int N, int K)
{
    __shared__ __align__(16) bf16_t Ads[2][4096];   // [128][32]
    __shared__ __align__(16) bf16_t Bds[2][4096];

    const int tid  = threadIdx.x;
    const int wave = tid >> 6;
    const int lane = tid & 63;
    const int m0 = blockIdx.y << 7;
    const int n0 = blockIdx.x << 7;
    const int wm = (wave >> 1) << 6;
    const int wn = (wave & 1) << 6;
    const int lr = lane & 15;
    const int lg = lane >> 4;

    // staging: wave handles chunks {wave, wave+4}; chunk = 16 rows x 32 cols (1KB)
    const int srow = lane >> 2;           // row within chunk
    const int scol = (lane & 3) << 3;     // elem col within row (8-elem groups)

    size_t aoff[2], boff[2];
    #pragma unroll
    for (int c = 0; c < 2; ++c) {
        const int row = (wave + 4 * c) * 16 + srow;
        const int m = m0 + row;
        const int ar = (AMAP == 1) ? (((m >> 10) << 11) + 1024 + (m & 1023)) : m;
        aoff[c] = (size_t)ar * K + scol;
        boff[c] = (size_t)(n0 + row) * K + scol;
    }

    f32x4 acc[4][4];
    #pragma unroll
    for (int i = 0; i < 4; ++i)
        #pragma unroll
        for (int j = 0; j < 4; ++j)
            #pragma unroll
            for (int r = 0; r < 4; ++r) acc[i][j][r] = 0.0f;

    const int nk = K >> 5;
    int cur = 0;

    // prologue: stage k-tile 0 into buf 0
    #pragma unroll
    for (int c = 0; c < 2; ++c) {
        gload16(A  + aoff[c], &Ads[0][(wave + 4 * c) << 9]);
        gload16(Bw + boff[c], &Bds[0][(wave + 4 * c) << 9]);
    }
    __syncthreads();

    for (int kt = 0; kt < nk; ++kt) {
        if (kt + 1 < nk) {
            const int k0 = (kt + 1) << 5;
            #pragma unroll
            for (int c = 0; c < 2; ++c) {
                gload16(A  + aoff[c] + k0, &Ads[cur ^ 1][(wave + 4 * c) << 9]);
                gload16(Bw + boff[c] + k0, &Bds[cur ^ 1][(wave + 4 * c) << 9]);
            }
        }
        bf16x8 af[4], bfr[4];
        #pragma unroll
        for (int i = 0; i < 4; ++i) {
            af[i]  = *reinterpret_cast<const bf16x8*>(&Ads[cur][(wm + i * 16 + lr) * 32 + lg * 8]);
            bfr[i] = *reinterpret_cast<const bf16x8*>(&Bds[cur][(wn + i * 16 + lr) * 32 + lg * 8]);
        }
        #pragma unroll
        for (int mi = 0; mi < 4; ++mi)
            #pragma unroll
            for (int ni = 0; ni < 4; ++ni)
                acc[mi][ni] = __builtin_amdgcn_mfma_f32_16x16x32_bf16(
                    af[mi], bfr[ni], acc[mi][ni], 0, 0, 0);
        __syncthreads();   // drains vmcnt (staged buf ready) + LDS reads done
        cur ^= 1;
    }

    // epilogue: lane holds C[m = wm+mi*16+lg*4+r][n = wn+ni*16+lr]
    #pragma unroll
    for (int mi = 0; mi < 4; ++mi)
        #pragma unroll
        for (int r = 0; r < 4; ++r) {
            const int m = m0 + wm + mi * 16 + lg * 4 + r;
            OutT* crow = C + (size_t)m * N + n0 + wn + lr;
            crow[0]  = (OutT)acc[mi][0][r];
            crow[16] = (OutT)acc[mi][1][r];
            crow[32] = (OutT)acc[mi][2][r];
            crow[48] = (OutT)acc[mi][3][r];
        }
}

// ---------------------------------------------------------------------------
// Fused per-head RMSNorm + RoPE, in place on bf16. One 64-lane wave per row.
// addr = base + (b*SLEN + s)*STRIDE + h*64 + lane
// ---------------------------------------------------------------------------
template<int NHEADS, int SLEN, int STRIDE>
__global__ __launch_bounds__(256)
void rms_rope(bf16_t* __restrict__ X, const float* __restrict__ gamma,
              const float* __restrict__ cosb, const float* __restrict__ sinb,
              int pos_off)
{
    const int row  = blockIdx.x * 4 + (threadIdx.x >> 6);
    const int lane = threadIdx.x & 63;
    const int b    = row / (SLEN * NHEADS);
    const int rem  = row - b * SLEN * NHEADS;
    const int s    = rem / NHEADS;
    const int h    = rem - s * NHEADS;

    const size_t idx = (size_t)(b * SLEN + s) * STRIDE + h * 64 + lane;
    const float x = (float)X[idx];
    float ss = x * x;
    #pragma unroll
    for (int o = 32; o >= 1; o >>= 1) ss += __shfl_xor(ss, o);
    const float r = rsqrtf(ss * (1.0f / 64.0f) + 1e-6f);
    const float qn = x * r * gamma[lane];
    const float partner = __shfl_xor(qn, 32);
    const float rot = (lane < 32) ? -partner : partner;
    const int pos = pos_off + s;
    const size_t cidx = ((size_t)b * Tt + pos) * 64 + lane;
    X[idx] = (bf16_t)(qn * cosb[cidx] + rot * sinb[cidx]);
}

// ---------------------------------------------------------------------------
// bf16 MFMA flash attention. Grid: (B*NH, Sq/64). Block: 256 (4 waves).
// Q layout [b][s][h*64+d] stride 2048; KV layout [b][t][1024]: K at g*64, V at 512+g*64.
// Output bf16 written IN PLACE over Q (each block reads its Q slice first).
// ---------------------------------------------------------------------------
__global__ __launch_bounds__(256)
void flash_mfma(const bf16_t* __restrict__ Qb, const bf16_t* __restrict__ KVb,
                bf16_t* __restrict__ Ob)
{
    const int bh = blockIdx.x;
    const int b  = bh >> 5;
    const int h  = bh & 31;
    const int g  = h >> 2;
    const int q0 = blockIdx.y << 6;
    const int tid  = threadIdx.x;
    const int wave = tid >> 6;
    const int lane = tid & 63;
    const int lr = lane & 15;
    const int lg = lane >> 4;

    __shared__ __align__(16) bf16_t Kt[64][72];      // [k][d]
    __shared__ __align__(16) bf16_t Vt[64][72];      // [d][t]
    __shared__ __align__(16) bf16_t Pq[4][16][72];   // per-wave [q][t]

    // Q fragments, direct global->reg (B-operand of K*Q^T)
    bf16x8 qf[2];
    {
        const bf16_t* qp = Qb + (size_t)(b * Sq + q0 + wave * 16 + lr) * 2048 + h * 64 + lg * 8;
        qf[0] = *reinterpret_cast<const bf16x8*>(qp);
        qf[1] = *reinterpret_cast<const bf16x8*>(qp + 32);
    }

    float m_ = -1e30f, l_ = 0.0f;
    f32x4 oacc[4];
    #pragma unroll
    for (int dt = 0; dt < 4; ++dt)
        #pragma unroll
        for (int j = 0; j < 4; ++j) oacc[dt][j] = 0.0f;

    for (int t0 = 0; t0 < Tt; t0 += 64) {
        __syncthreads();
        // stage K tile: [k][d]
        {
            const int kr = tid >> 2;
            const int c  = (tid & 3) * 16;
            const bf16_t* kp = KVb + (size_t)(b * Tt + t0 + kr) * 1024 + g * 64 + c;
            *reinterpret_cast<bf16x8*>(&Kt[kr][c])     = *reinterpret_cast<const bf16x8*>(kp);
            *reinterpret_cast<bf16x8*>(&Kt[kr][c + 8]) = *reinterpret_cast<const bf16x8*>(kp + 8);
        }
        // stage V tile transposed: [d][t]
        {
            const int tb = tid >> 4;
            const int db = tid & 15;
            const bf16_t* vp = KVb + (size_t)(b * Tt + t0 + tb * 4) * 1024 + 512 + g * 64 + db * 4;
            const bf16x4 v0 = *reinterpret_cast<const bf16x4*>(vp);
            const bf16x4 v1 = *reinterpret_cast<const bf16x4*>(vp + 1024);
            const bf16x4 v2 = *reinterpret_cast<const bf16x4*>(vp + 2048);
            const bf16x4 v3 = *reinterpret_cast<const bf16x4*>(vp + 3072);
            #pragma unroll
            for (int j = 0; j < 4; ++j) {
                bf16x4 w;
                w[0] = v0[j]; w[1] = v1[j]; w[2] = v2[j]; w[3] = v3[j];
                *reinterpret_cast<bf16x4*>(&Vt[db * 4 + j][tb * 4]) = w;
            }
        }
        __syncthreads();

        // QK^T (swapped): S^T = K * Q^T
        f32x4 sc[4];
        #pragma unroll
        for (int kt = 0; kt < 4; ++kt) {
            #pragma unroll
            for (int j = 0; j < 4; ++j) sc[kt][j] = 0.0f;
            const bf16x8 kf0 = *reinterpret_cast<const bf16x8*>(&Kt[kt * 16 + lr][lg * 8]);
            const bf16x8 kf1 = *reinterpret_cast<const bf16x8*>(&Kt[kt * 16 + lr][32 + lg * 8]);
            sc[kt] = __builtin_amdgcn_mfma_f32_16x16x32_bf16(kf0, qf[0], sc[kt], 0, 0, 0);
            sc[kt] = __builtin_amdgcn_mfma_f32_16x16x32_bf16(kf1, qf[1], sc[kt], 0, 0, 0);
        }

        // online softmax: lane holds 16 scores for q = lr
        float p[16];
        float mx = -1e30f;
        #pragma unroll
        for (int kt = 0; kt < 4; ++kt)
            #pragma unroll
            for (int j = 0; j < 4; ++j) {
                const float v = sc[kt][j] * 0.125f;
                p[kt * 4 + j] = v;
                mx = fmaxf(mx, v);
            }
        mx = fmaxf(mx, __shfl_xor(mx, 16));
        mx = fmaxf(mx, __shfl_xor(mx, 32));
        const float mn = fmaxf(m_, mx);
        const float resc = __expf(m_ - mn);
        m_ = mn;
        float rs = 0.0f;
        #pragma unroll
        for (int i = 0; i < 16; ++i) { p[i] = __expf(p[i] - mn); rs += p[i]; }
        rs += __shfl_xor(rs, 16);
        rs += __shfl_xor(rs, 32);
        l_ = l_ * resc + rs;
        #pragma unroll
        for (int dt = 0; dt < 4; ++dt)
            #pragma unroll
            for (int j = 0; j < 4; ++j) oacc[dt][j] *= resc;

        // write P (bf16) to per-wave LDS
        #pragma unroll
        for (int kt = 0; kt < 4; ++kt) {
            bf16x4 pw;
            #pragma unroll
            for (int j = 0; j < 4; ++j) pw[j] = (bf16_t)p[kt * 4 + j];
            *reinterpret_cast<bf16x4*>(&Pq[wave][lr][kt * 16 + lg * 4]) = pw;
        }
        __syncthreads();

        // PV: O^T = V^T * P^T
        bf16x8 pb[2];
        pb[0] = *reinterpret_cast<const bf16x8*>(&Pq[wave][lr][lg * 8]);
        pb[1] = *reinterpret_cast<const bf16x8*>(&Pq[wave][lr][32 + lg * 8]);
        #pragma unroll
        for (int dt = 0; dt < 4; ++dt) {
            const bf16x8 vf0 = *reinterpret_cast<const bf16x8*>(&Vt[dt * 16 + lr][lg * 8]);
            const bf16x8 vf1 = *reinterpret_cast<const bf16x8*>(&Vt[dt * 16 + lr][32 + lg * 8]);
            oacc[dt] = __builtin_amdgcn_mfma_f32_16x16x32_bf16(vf0, pb[0], oacc[dt], 0, 0, 0);
            oacc[dt] = __builtin_amdgcn_mfma_f32_16x16x32_bf16(vf1, pb[1], oacc[dt], 0, 0, 0);
        }
    }

    // finalize: write bf16 attn in place
    const float inv = 1.0f / l_;
    #pragma unroll
    for (int dt = 0; dt < 4; ++dt) {
        bf16x4 o;
        #pragma unroll
        for (int j = 0; j < 4; ++j) o[j] = (bf16_t)(oacc[dt][j] * inv);
        *reinterpret_cast<bf16x4*>(
            Ob + (size_t)(b * Sq + q0 + wave * 16 + lr) * 2048 + h * 64 + dt * 16 + lg * 4) = o;
    }
}

// ---------------------------------------------------------------------------
extern "C" void kernel_launch(void* const* d_in, const int* in_sizes, int n_in,
                              void* d_out, int out_size, void* d_ws, size_t ws_size,
                              hipStream_t stream)
{
    const float* hs   = (const float*)d_in[0];
    const float* tctx = (const float*)d_in[1];
    const float* cosb = (const float*)d_in[2];
    const float* sinb = (const float*)d_in[3];
    const float* Wq   = (const float*)d_in[4];
    const float* Wk   = (const float*)d_in[5];
    const float* Wv   = (const float*)d_in[6];
    const float* Wo   = (const float*)d_in[7];
    const float* qg   = (const float*)d_in[8];
    const float* kg   = (const float*)d_in[9];
    float* out = (float*)d_out;

    // workspace layout (bf16 elems): total 23,068,672 elems = 46.1 MB
    bf16_t* W     = (bf16_t*)d_ws;
    bf16_t* kvinb = W;                    // [B][2048][2048] concat(kv_ctx, hidden): 8,388,608
    bf16_t* Wqb   = kvinb + 8388608;      // [2048][2048]: 4,194,304
    bf16_t* Wkvb  = Wqb + 4194304;        // [1024][2048] (Wk rows 0-511, Wv rows 512-1023): 2,097,152
    bf16_t* Qb    = Wkvb + 2097152;       // [2048][2048] q / attn in-place: 4,194,304
    bf16_t* KVb   = Qb + 4194304;         // [4096][1024] k|v: 4,194,304
    bf16_t* Wob   = kvinb;                // reused after the first two GEMMs

    // converts
    cvt_concat<<<2048, 256, 0, stream>>>(tctx, kvinb, 0);
    cvt_concat<<<2048, 256, 0, stream>>>(hs,   kvinb, 1024 * 2048);
    cvt_bf16<<<2048, 256, 0, stream>>>(Wq, Wqb, 4194304);
    cvt_bf16<<<512,  256, 0, stream>>>(Wk, Wkvb, 1048576);
    cvt_bf16<<<512,  256, 0, stream>>>(Wv, Wkvb + 1048576, 1048576);

    // Q projection: A = hidden rows of kvinb (AMAP=1)
    gemm_mfma<1, bf16_t><<<dim3(16, 16), 256, 0, stream>>>(
        kvinb, Wqb, Qb, Bc * Sq, NH * HD, HID);

    // KV projection: [4096][1024]
    gemm_mfma<0, bf16_t><<<dim3(8, 32), 256, 0, stream>>>(
        kvinb, Wkvb, KVb, Bc * Tt, 2 * NKV * HD, HID);

    // convert Wo into kvinb's space (kvinb consumed above)
    cvt_bf16<<<2048, 256, 0, stream>>>(Wo, Wob, 4194304);

    // RMSNorm + RoPE in place
    rms_rope<NH, Sq, 2048><<<(Bc * Sq * NH) / 4, 256, 0, stream>>>(Qb, qg, cosb, sinb, CTX);
    rms_rope<NKV, Tt, 1024><<<(Bc * Tt * NKV) / 4, 256, 0, stream>>>(KVb, kg, cosb, sinb, 0);

    // flash attention (bf16 MFMA), bf16 output in place over Q
    flash_mfma<<<dim3(Bc * NH, Sq / 64), 256, 0, stream>>>(Qb, KVb, Qb);

    // output projection: attn(bf16) @ Wo^T -> fp32 out
    gemm_mfma<0, float><<<dim3(16, 16), 256, 0, stream>>>(
        Qb, Wob, out, Bc * Sq, HID, NH * HD);
}

// Round 4
// 216.011 us; speedup vs baseline: 6.4559x; 1.2419x over previous
//
#include <hip/hip_runtime.h>
#include <hip/hip_bf16.h>
#include <cmath>

// Problem constants
constexpr int Bc  = 2;
constexpr int Sq  = 1024;   // query seq len
constexpr int CTX = 1024;
constexpr int Tt  = 2048;   // total kv len
constexpr int HID = 2048;
constexpr int NH  = 32;
constexpr int NKV = 8;
constexpr int HD  = 64;

typedef __bf16 bf16_t;
typedef bf16_t bf16x8 __attribute__((ext_vector_type(8)));
typedef bf16_t bf16x4 __attribute__((ext_vector_type(4)));
typedef bf16_t bf16x2 __attribute__((ext_vector_type(2)));
typedef float  f32x4  __attribute__((ext_vector_type(4)));

// ---------------------------------------------------------------------------
// async global->LDS, 16B per lane. LDS dest wave-uniform base (+lane*16).
// ---------------------------------------------------------------------------
__device__ __forceinline__ void gload16(const bf16_t* g, bf16_t* l)
{
    __builtin_amdgcn_global_load_lds(
        (const __attribute__((address_space(1))) void*)g,
        (__attribute__((address_space(3))) void*)l, 16, 0, 0);
}

// ---------------------------------------------------------------------------
// fp32 -> bf16 elementwise convert (8 elems/thread)
// ---------------------------------------------------------------------------
__global__ __launch_bounds__(256)
void cvt_bf16(const float* __restrict__ src, bf16_t* __restrict__ dst, int n)
{
    const int i = (blockIdx.x * 256 + threadIdx.x) * 8;
    if (i >= n) return;
    const float4 a = *reinterpret_cast<const float4*>(src + i);
    const float4 b = *reinterpret_cast<const float4*>(src + i + 4);
    bf16x8 o;
    o[0] = (bf16_t)a.x; o[1] = (bf16_t)a.y; o[2] = (bf16_t)a.z; o[3] = (bf16_t)a.w;
    o[4] = (bf16_t)b.x; o[5] = (bf16_t)b.y; o[6] = (bf16_t)b.z; o[7] = (bf16_t)b.w;
    *reinterpret_cast<bf16x8*>(dst + i) = o;
}

// fused Wq|Wk|Wv convert into contiguous dst (Wqb then Wkv)
__global__ __launch_bounds__(256)
void cvt_w3(const float* __restrict__ wq, const float* __restrict__ wk,
            const float* __restrict__ wv, bf16_t* __restrict__ dst)
{
    const int i = (blockIdx.x * 256 + threadIdx.x) * 8;
    const float* src;
    int off;
    if (i < 4194304)      { src = wq; off = i; }
    else if (i < 5242880) { src = wk; off = i - 4194304; }
    else                  { src = wv; off = i - 5242880; }
    const float4 a = *reinterpret_cast<const float4*>(src + off);
    const float4 b = *reinterpret_cast<const float4*>(src + off + 4);
    bf16x8 o;
    o[0] = (bf16_t)a.x; o[1] = (bf16_t)a.y; o[2] = (bf16_t)a.z; o[3] = (bf16_t)a.w;
    o[4] = (bf16_t)b.x; o[5] = (bf16_t)b.y; o[6] = (bf16_t)b.z; o[7] = (bf16_t)b.w;
    *reinterpret_cast<bf16x8*>(dst + i) = o;
}

// fp32 -> bf16 with per-batch concat placement: src [B][2^21], dst [B][2^22] at dstOff
__global__ __launch_bounds__(256)
void cvt_concat(const float* __restrict__ src, bf16_t* __restrict__ dst, int dstOff)
{
    const int i   = (blockIdx.x * 256 + threadIdx.x) * 8;
    const int b   = i >> 21;
    const int rem = i & ((1 << 21) - 1);
    const float4 a = *reinterpret_cast<const float4*>(src + i);
    const float4 c = *reinterpret_cast<const float4*>(src + i + 4);
    bf16x8 o;
    o[0] = (bf16_t)a.x; o[1] = (bf16_t)a.y; o[2] = (bf16_t)a.z; o[3] = (bf16_t)a.w;
    o[4] = (bf16_t)c.x; o[5] = (bf16_t)c.y; o[6] = (bf16_t)c.z; o[7] = (bf16_t)c.w;
    *reinterpret_cast<bf16x8*>(dst + (((size_t)b << 22) + dstOff + rem)) = o;
}

// ---------------------------------------------------------------------------
// bf16 MFMA GEMM:  C[m,n] = sum_k A[m,k] * B[n,k]   (both row-major K-contig)
// BM=64, BN=128, BK=32, 256 threads (4 waves 2x2: wave = 32m x 64n, 2x4 frags).
// Double-buffered LDS via global_load_lds, one barrier per K-step.
// AMAP=1: A row m remapped to kv-concat hidden rows.
// ---------------------------------------------------------------------------
template<int AMAP, typename OutT>
__global__ __launch_bounds__(256)
void gemm_mfma(const bf16_t* __restrict__ A, const bf16_t* __restrict__ Bw,
               OutT* __restrict__ C, int M, int N, int K)
{
    __shared__ __align__(16) bf16_t Ads[2][2048];   // [64][32]
    __shared__ __align__(16) bf16_t Bds[2][4096];   // [128][32]

    const int tid  = threadIdx.x;
    const int wave = tid >> 6;
    const int lane = tid & 63;
    const int m0 = blockIdx.y << 6;
    const int n0 = blockIdx.x << 7;
    const int wm = (wave >> 1) << 5;   // 0,32
    const int wn = (wave & 1) << 6;    // 0,64
    const int lr = lane & 15;
    const int lg = lane >> 4;

    const int srow = tid >> 2;         // 0..63
    const int scol = (tid & 3) << 3;   // 0,8,16,24

    const int am = m0 + srow;
    const int ar = (AMAP == 1) ? (((am >> 10) << 11) + 1024 + (am & 1023)) : am;
    const size_t aoff  = (size_t)ar * K + scol;
    const size_t boff0 = (size_t)(n0 + srow) * K + scol;
    const size_t boff1 = (size_t)(n0 + 64 + srow) * K + scol;

    f32x4 acc[2][4];
    #pragma unroll
    for (int i = 0; i < 2; ++i)
        #pragma unroll
        for (int j = 0; j < 4; ++j)
            #pragma unroll
            for (int r = 0; r < 4; ++r) acc[i][j][r] = 0.0f;

    const int nk = K >> 5;
    int cur = 0;

    // prologue: stage k-tile 0 into buf 0
    gload16(A  + aoff,  &Ads[0][wave << 9]);
    gload16(Bw + boff0, &Bds[0][wave << 9]);
    gload16(Bw + boff1, &Bds[0][2048 + (wave << 9)]);
    __syncthreads();

    for (int kt = 0; kt < nk; ++kt) {
        if (kt + 1 < nk) {
            const int k0 = (kt + 1) << 5;
            gload16(A  + aoff  + k0, &Ads[cur ^ 1][wave << 9]);
            gload16(Bw + boff0 + k0, &Bds[cur ^ 1][wave << 9]);
            gload16(Bw + boff1 + k0, &Bds[cur ^ 1][2048 + (wave << 9)]);
        }
        bf16x8 af[2], bfr[4];
        #pragma unroll
        for (int i = 0; i < 2; ++i)
            af[i]  = *reinterpret_cast<const bf16x8*>(&Ads[cur][(wm + i * 16 + lr) * 32 + lg * 8]);
        #pragma unroll
        for (int i = 0; i < 4; ++i)
            bfr[i] = *reinterpret_cast<const bf16x8*>(&Bds[cur][(wn + i * 16 + lr) * 32 + lg * 8]);
        #pragma unroll
        for (int mi = 0; mi < 2; ++mi)
            #pragma unroll
            for (int ni = 0; ni < 4; ++ni)
                acc[mi][ni] = __builtin_amdgcn_mfma_f32_16x16x32_bf16(
                    af[mi], bfr[ni], acc[mi][ni], 0, 0, 0);
        __syncthreads();   // drains vmcnt (next buf staged) + LDS reads done
        cur ^= 1;
    }

    // epilogue: lane holds C[m = wm+mi*16+lg*4+r][n = wn+ni*16+lr]
    #pragma unroll
    for (int mi = 0; mi < 2; ++mi)
        #pragma unroll
        for (int r = 0; r < 4; ++r) {
            const int m = m0 + wm + mi * 16 + lg * 4 + r;
            OutT* crow = C + (size_t)m * N + n0 + wn + lr;
            crow[0]  = (OutT)acc[mi][0][r];
            crow[16] = (OutT)acc[mi][1][r];
            crow[32] = (OutT)acc[mi][2][r];
            crow[48] = (OutT)acc[mi][3][r];
        }
}

// ---------------------------------------------------------------------------
// Fused per-head RMSNorm + RoPE, in place on bf16. One 64-lane wave per row.
// ---------------------------------------------------------------------------
template<int NHEADS, int SLEN, int STRIDE>
__global__ __launch_bounds__(256)
void rms_rope(bf16_t* __restrict__ X, const float* __restrict__ gamma,
              const float* __restrict__ cosb, const float* __restrict__ sinb,
              int pos_off)
{
    const int row  = blockIdx.x * 4 + (threadIdx.x >> 6);
    const int lane = threadIdx.x & 63;
    const int b    = row / (SLEN * NHEADS);
    const int rem  = row - b * SLEN * NHEADS;
    const int s    = rem / NHEADS;
    const int h    = rem - s * NHEADS;

    const size_t idx = (size_t)(b * SLEN + s) * STRIDE + h * 64 + lane;
    const float x = (float)X[idx];
    float ss = x * x;
    #pragma unroll
    for (int o = 32; o >= 1; o >>= 1) ss += __shfl_xor(ss, o);
    const float r = rsqrtf(ss * (1.0f / 64.0f) + 1e-6f);
    const float qn = x * r * gamma[lane];
    const float partner = __shfl_xor(qn, 32);
    const float rot = (lane < 32) ? -partner : partner;
    const int pos = pos_off + s;
    const size_t cidx = ((size_t)b * Tt + pos) * 64 + lane;
    X[idx] = (bf16_t)(qn * cosb[cidx] + rot * sinb[cidx]);
}

// ---------------------------------------------------------------------------
// bf16 MFMA flash attention, 8 waves (512 thr), QBLK=128, KV tile 64,
// double-buffered K/V with register prefetch: ONE barrier per tile.
// Grid: (B*NH, Sq/128). Q layout [b][s][h*64+d] stride 2048;
// KV layout [b][t][1024]: K at g*64, V at 512+g*64.
// Output bf16 written in place over Q.
// ---------------------------------------------------------------------------
__global__ __launch_bounds__(512)
void flash_mfma(const bf16_t* __restrict__ Qb, const bf16_t* __restrict__ KVb,
                bf16_t* __restrict__ Ob)
{
    const int bh = blockIdx.x;
    const int b  = bh >> 5;
    const int h  = bh & 31;
    const int g  = h >> 2;
    const int q0 = blockIdx.y << 7;
    const int tid  = threadIdx.x;
    const int wave = tid >> 6;
    const int lane = tid & 63;
    const int lr = lane & 15;
    const int lg = lane >> 4;

    __shared__ __align__(16) bf16_t Kd[2][64][68];      // [k][d]
    __shared__ __align__(16) bf16_t Vd[2][64][68];      // [d][t]
    __shared__ __align__(16) bf16_t Pq[8][16][68];      // per-wave [q][t]

    // staging assignment (block-wide, 512 threads)
    const int kr = tid >> 3;            // K row 0..63
    const int kc = (tid & 7) << 3;      // K col 0,8,..,56
    const int tp = tid >> 4;            // V t-pair 0..31
    const int d0 = (tid & 15) << 2;     // V d-group

    const size_t kbase = (size_t)(b * Tt) * 1024 + g * 64;

    // Q fragments (B-operand of S^T = K*Q^T)
    bf16x8 qf[2];
    {
        const bf16_t* qp = Qb + (size_t)(b * Sq + q0 + wave * 16 + lr) * 2048 + h * 64 + lg * 8;
        qf[0] = *reinterpret_cast<const bf16x8*>(qp);
        qf[1] = *reinterpret_cast<const bf16x8*>(qp + 32);
    }

    float m_ = -1e30f, l_ = 0.0f;
    f32x4 oacc[4];
    #pragma unroll
    for (int dt = 0; dt < 4; ++dt)
        #pragma unroll
        for (int j = 0; j < 4; ++j) oacc[dt][j] = 0.0f;

    // prologue: load tile 0 into regs, write buf 0
    bf16x8 kreg;
    bf16x4 vr0, vr1;
    {
        kreg = *reinterpret_cast<const bf16x8*>(KVb + kbase + (size_t)kr * 1024 + kc);
        const bf16_t* vp = KVb + kbase + (size_t)(tp * 2) * 1024 + 512 + d0;
        vr0 = *reinterpret_cast<const bf16x4*>(vp);
        vr1 = *reinterpret_cast<const bf16x4*>(vp + 1024);
    }
    *reinterpret_cast<bf16x8*>(&Kd[0][kr][kc]) = kreg;
    #pragma unroll
    for (int j = 0; j < 4; ++j) {
        bf16x2 w; w[0] = vr0[j]; w[1] = vr1[j];
        *reinterpret_cast<bf16x2*>(&Vd[0][d0 + j][tp * 2]) = w;
    }
    __syncthreads();

    constexpr float Cs = 0.125f * 1.44269504088896f;   // scale * log2(e)
    int cur = 0;

    for (int t0 = 0; t0 < Tt; t0 += 64) {
        const bool more = (t0 + 64 < Tt);
        if (more) {
            const size_t tb = kbase + (size_t)(t0 + 64) * 1024;
            kreg = *reinterpret_cast<const bf16x8*>(KVb + tb + (size_t)kr * 1024 + kc);
            const bf16_t* vp = KVb + tb + (size_t)(tp * 2) * 1024 + 512 + d0;
            vr0 = *reinterpret_cast<const bf16x4*>(vp);
            vr1 = *reinterpret_cast<const bf16x4*>(vp + 1024);
        }

        // QK^T (swapped): S^T = K * Q^T
        f32x4 sc[4];
        #pragma unroll
        for (int kt = 0; kt < 4; ++kt) {
            #pragma unroll
            for (int j = 0; j < 4; ++j) sc[kt][j] = 0.0f;
            const bf16x8 kf0 = *reinterpret_cast<const bf16x8*>(&Kd[cur][kt * 16 + lr][lg * 8]);
            const bf16x8 kf1 = *reinterpret_cast<const bf16x8*>(&Kd[cur][kt * 16 + lr][32 + lg * 8]);
            sc[kt] = __builtin_amdgcn_mfma_f32_16x16x32_bf16(kf0, qf[0], sc[kt], 0, 0, 0);
            sc[kt] = __builtin_amdgcn_mfma_f32_16x16x32_bf16(kf1, qf[1], sc[kt], 0, 0, 0);
        }

        // online softmax in log2 domain, defer-rescale (THR=8)
        float v[16];
        float mx = -3.0e38f;
        #pragma unroll
        for (int kt = 0; kt < 4; ++kt)
            #pragma unroll
            for (int j = 0; j < 4; ++j) {
                const float t = sc[kt][j] * Cs;
                v[kt * 4 + j] = t;
                mx = fmaxf(mx, t);
            }
        mx = fmaxf(mx, __shfl_xor(mx, 16));
        mx = fmaxf(mx, __shfl_xor(mx, 32));
        if (__any(mx > m_ + 8.0f)) {
            const float mn   = fmaxf(m_, mx);
            const float resc = exp2f(m_ - mn);
            l_ *= resc;
            #pragma unroll
            for (int dt = 0; dt < 4; ++dt)
                #pragma unroll
                for (int j = 0; j < 4; ++j) oacc[dt][j] *= resc;
            m_ = mn;
        }
        float rs = 0.0f;
        #pragma unroll
        for (int i = 0; i < 16; ++i) { v[i] = exp2f(v[i] - m_); rs += v[i]; }
        rs += __shfl_xor(rs, 16);
        rs += __shfl_xor(rs, 32);
        l_ += rs;

        // write P (bf16) to per-wave LDS (wave-local: no barrier needed)
        #pragma unroll
        for (int kt = 0; kt < 4; ++kt) {
            bf16x4 pw;
            #pragma unroll
            for (int j = 0; j < 4; ++j) pw[j] = (bf16_t)v[kt * 4 + j];
            *reinterpret_cast<bf16x4*>(&Pq[wave][lr][kt * 16 + lg * 4]) = pw;
        }

        // PV: O^T = V^T * P^T
        bf16x8 pb[2];
        pb[0] = *reinterpret_cast<const bf16x8*>(&Pq[wave][lr][lg * 8]);
        pb[1] = *reinterpret_cast<const bf16x8*>(&Pq[wave][lr][32 + lg * 8]);
        #pragma unroll
        for (int dt = 0; dt < 4; ++dt) {
            const bf16x8 vf0 = *reinterpret_cast<const bf16x8*>(&Vd[cur][dt * 16 + lr][lg * 8]);
            const bf16x8 vf1 = *reinterpret_cast<const bf16x8*>(&Vd[cur][dt * 16 + lr][32 + lg * 8]);
            oacc[dt] = __builtin_amdgcn_mfma_f32_16x16x32_bf16(vf0, pb[0], oacc[dt], 0, 0, 0);
            oacc[dt] = __builtin_amdgcn_mfma_f32_16x16x32_bf16(vf1, pb[1], oacc[dt], 0, 0, 0);
        }

        // stage next tile into the other buffer; single barrier per tile
        if (more) {
            *reinterpret_cast<bf16x8*>(&Kd[cur ^ 1][kr][kc]) = kreg;
            #pragma unroll
            for (int j = 0; j < 4; ++j) {
                bf16x2 w; w[0] = vr0[j]; w[1] = vr1[j];
                *reinterpret_cast<bf16x2*>(&Vd[cur ^ 1][d0 + j][tp * 2]) = w;
            }
            __syncthreads();
        }
        cur ^= 1;
    }

    // finalize: write bf16 attn in place
    const float inv = 1.0f / l_;
    #pragma unroll
    for (int dt = 0; dt < 4; ++dt) {
        bf16x4 o;
        #pragma unroll
        for (int j = 0; j < 4; ++j) o[j] = (bf16_t)(oacc[dt][j] * inv);
        *reinterpret_cast<bf16x4*>(
            Ob + (size_t)(b * Sq + q0 + wave * 16 + lr) * 2048 + h * 64 + dt * 16 + lg * 4) = o;
    }
}

// ---------------------------------------------------------------------------
extern "C" void kernel_launch(void* const* d_in, const int* in_sizes, int n_in,
                              void* d_out, int out_size, void* d_ws, size_t ws_size,
                              hipStream_t stream)
{
    const float* hs   = (const float*)d_in[0];
    const float* tctx = (const float*)d_in[1];
    const float* cosb = (const float*)d_in[2];
    const float* sinb = (const float*)d_in[3];
    const float* Wq   = (const float*)d_in[4];
    const float* Wk   = (const float*)d_in[5];
    const float* Wv   = (const float*)d_in[6];
    const float* Wo   = (const float*)d_in[7];
    const float* qg   = (const float*)d_in[8];
    const float* kg   = (const float*)d_in[9];
    float* out = (float*)d_out;

    // workspace layout (bf16 elems): total 23,068,672 elems = 46.1 MB
    bf16_t* W     = (bf16_t*)d_ws;
    bf16_t* kvinb = W;                    // [B][2048][2048] concat(ctx, hidden): 8,388,608
    bf16_t* Wqb   = kvinb + 8388608;      // [2048][2048]: 4,194,304
    bf16_t* Wkvb  = Wqb + 4194304;        // [1024][2048]: 2,097,152 (contig after Wqb)
    bf16_t* Qb    = Wkvb + 2097152;       // [2048][2048] q / attn in-place: 4,194,304
    bf16_t* KVb   = Qb + 4194304;         // [4096][1024] k|v: 4,194,304
    bf16_t* Wob   = kvinb;                // reused after the first two GEMMs

    // converts
    cvt_concat<<<2048, 256, 0, stream>>>(tctx, kvinb, 0);
    cvt_concat<<<2048, 256, 0, stream>>>(hs,   kvinb, 1024 * 2048);
    cvt_w3<<<3072, 256, 0, stream>>>(Wq, Wk, Wv, Wqb);

    // Q projection: A = hidden rows of kvinb (AMAP=1), M=2048 N=2048
    gemm_mfma<1, bf16_t><<<dim3(16, 32), 256, 0, stream>>>(
        kvinb, Wqb, Qb, Bc * Sq, NH * HD, HID);

    // KV projection: M=4096 N=1024
    gemm_mfma<0, bf16_t><<<dim3(8, 64), 256, 0, stream>>>(
        kvinb, Wkvb, KVb, Bc * Tt, 2 * NKV * HD, HID);

    // convert Wo into kvinb's space (kvinb consumed above)
    cvt_bf16<<<2048, 256, 0, stream>>>(Wo, Wob, 4194304);

    // RMSNorm + RoPE in place
    rms_rope<NH, Sq, 2048><<<(Bc * Sq * NH) / 4, 256, 0, stream>>>(Qb, qg, cosb, sinb, CTX);
    rms_rope<NKV, Tt, 1024><<<(Bc * Tt * NKV) / 4, 256, 0, stream>>>(KVb, kg, cosb, sinb, 0);

    // flash attention (bf16 MFMA), bf16 output in place over Q
    flash_mfma<<<dim3(Bc * NH, Sq / 128), 512, 0, stream>>>(Qb, KVb, Qb);

    // output projection: attn(bf16) @ Wo^T -> fp32 out, M=2048 N=2048
    gemm_mfma<0, float><<<dim3(16, 32), 256, 0, stream>>>(
        Qb, Wob, out, Bc * Sq, HID, NH * HD);
}